// Round 7
// baseline (714.051 us; speedup 1.0000x reference)
//
#include <hip/hip_runtime.h>
#include <hip/hip_bf16.h>
#include <math.h>

typedef unsigned short u16;
typedef short s16x8 __attribute__((ext_vector_type(8)));
typedef float f32x4 __attribute__((ext_vector_type(4)));

#define BS_   32768      // B*S
#define SEQ_  4096
#define DM_   512
#define FF_   1024
#define FIN_  586
#define FINP_ 640        // emb K padded to multiple of 64
#define PADE  264        // epilogue LDS stride (u16) for 256-wide tile

__device__ __forceinline__ u16 f2b(float f) {
    __hip_bfloat16 h = __float2bfloat16(f);      // RNE, hw v_cvt on gfx950
    return *reinterpret_cast<u16*>(&h);
}
__device__ __forceinline__ float b2f(u16 h) {
    union { unsigned u; float f; } a; a.u = ((unsigned)h) << 16;
    return a.f;
}

typedef __attribute__((address_space(1))) const unsigned gu32;
typedef __attribute__((address_space(3))) unsigned lu32;
__device__ __forceinline__ void glds16(const void* g, void* l) {
    __builtin_amdgcn_global_load_lds((gu32*)g, (lu32*)l, 16, 0, 0);
}

// ---------------- batched weight transpose + bf16 convert (one launch) ----------------
__device__ __forceinline__ void tr_tile(const float* __restrict__ W, u16* __restrict__ Wt,
                                        int K, int N, int Kpad, int tidx, int ktiles,
                                        float (*t)[33]) {
    int kb = (tidx % ktiles) << 5, nb = (tidx / ktiles) << 5;
    int tx = threadIdx.x, ty = threadIdx.y;          // 32 x 8
#pragma unroll
    for (int j = 0; j < 32; j += 8) {
        int k = kb + ty + j;
        t[ty + j][tx] = (k < K) ? W[(size_t)k * N + nb + tx] : 0.f;
    }
    __syncthreads();
#pragma unroll
    for (int j = 0; j < 32; j += 8) {
        Wt[(size_t)(nb + ty + j) * Kpad + kb + tx] = f2b(t[tx][ty + j]);
    }
}

__global__ void k_tr_all(const float* __restrict__ W0, const float* __restrict__ Wq,
                         const float* __restrict__ Wk, const float* __restrict__ Wv,
                         const float* __restrict__ Wo, const float* __restrict__ W1,
                         const float* __restrict__ W2,
                         u16* __restrict__ W0t, u16* __restrict__ Wqkv,
                         u16* __restrict__ Wot, u16* __restrict__ W1t,
                         u16* __restrict__ W2t) {
    __shared__ float t[32][33];
    int b = blockIdx.x;
    if (b < 320) { tr_tile(W0, W0t, FIN_, DM_, FINP_, b, 20, t); return; }   // 20x16 tiles
    b -= 320;
    int l = b >> 11;              // 2048 tiles per layer
    int r = b & 2047;
    if (r < 768) {                // q,k,v : 256 tiles each
        int sel = r >> 8, ti = r & 255;
        const float* src = sel == 0 ? Wq : (sel == 1 ? Wk : Wv);
        tr_tile(src + (size_t)l * 262144, Wqkv + (size_t)l * 786432 + (size_t)sel * 262144,
                512, 512, 512, ti, 16, t);
    } else if (r < 1024) {
        tr_tile(Wo + (size_t)l * 262144, Wot + (size_t)l * 262144, 512, 512, 512, r - 768, 16, t);
    } else if (r < 1536) {
        tr_tile(W1 + (size_t)l * 524288, W1t + (size_t)l * 524288, 512, 1024, 512, r - 1024, 16, t);
    } else {
        tr_tile(W2 + (size_t)l * 524288, W2t + (size_t)l * 524288, 1024, 512, 1024, r - 1536, 32, t);
    }
}

// ---------------- embeddings -> bf16 padded [BS][640] ---------------------------------
__global__ __launch_bounds__(256)
void k_emb(const float* __restrict__ E, u16* __restrict__ Ep) {
    const int total8 = BS_ * (FINP_ / 8);
    for (int i = blockIdx.x * 256 + threadIdx.x; i < total8; i += gridDim.x * 256) {
        int rr = i / (FINP_ / 8), c = (i % (FINP_ / 8)) * 8;
        const float* rp = E + (size_t)rr * FIN_ + c;
        s16x8 o;
#pragma unroll
        for (int e = 0; e < 8; ++e) {
            float v = (c + e < FIN_) ? rp[e] : 0.f;
            o[e] = (short)f2b(v);
        }
        *(s16x8*)(Ep + (size_t)rr * FINP_ + c) = o;
    }
}

// ---------------- MFMA GEMM: 256x256, 8 waves, counted-vmcnt 4-phase schedule ---------
// BK=64, 2-dbuf LDS (128KB), glds 16B (linear dest, swizzled SOURCE), XCD swizzle.
// Per-wave stage order per tile: batch6=[A64_0,A64_2,B64_0..3] @q0, batch2=[A64_1,A64_3] @q1.
// Sync points per tile: boundary {vmcnt(2); s_barrier} certifies batch6 of tile t;
// pre-q2 {vmcnt(8) (last tile: 0); s_barrier} certifies batch2. Never drain in-loop.
// EPI: 0 = bias only, 1 = QKV split (feat on q,k), 2 = residual-add, 3 = relu
template<int EPI>
__global__ __launch_bounds__(512, 2)
void k_gemm(const u16* __restrict__ A, const u16* __restrict__ Bt,
            const float* __restrict__ bias0, const float* __restrict__ bias1,
            const float* __restrict__ bias2,
            const u16* __restrict__ resid,
            u16* __restrict__ out0, u16* __restrict__ out1, u16* __restrict__ out2,
            int M, int N, int K, int NT) {
    // u16 layout: A buf0 [0,16384) | A buf1 [16384,32768) | B buf0 [32768,49152) | B buf1 [49152,65536)
    __shared__ __align__(16) u16 smem[65536];      // 128 KB

    const int nwg = gridDim.x;
    const int cpx = nwg >> 3;                      // nwg % 8 == 0 for all launches here
    const int wg = (blockIdx.x & 7) * cpx + (blockIdx.x >> 3);
    const int mt = wg / NT, ntl = wg - mt * NT;
    const int m0 = mt << 8, n0 = ntl << 8;
    const int tid = threadIdx.x;
    const int wid = tid >> 6, l = tid & 63;
    const int wr = wid >> 2, wc = wid & 3;         // 2M x 4N waves; wave tile 128x64
    const int lr = l & 15, lg = l >> 4;

    // staging map: 512 thr x 16B = one 64-row group of 64 cols per glds
    const int srow = tid >> 3;                     // 0..63
    const int gchunk = (((tid & 7) ^ (srow & 7)) & 7) << 3;   // swizzled source k-offset
    const u16* Abase = A + (size_t)(m0 + srow) * K + gchunk;
    const u16* Bbase = Bt + (size_t)(n0 + srow) * K + gchunk;

    auto stA = [&](int d, int tt, int h) {         // A rows h*64..h*64+63 of K-tile tt
        glds16(Abase + (size_t)tt * 64 + (size_t)(h * 64) * K,
               smem + d * 16384 + h * 4096 + tid * 8);
    };
    auto stB = [&](int d, int tt, int h) {
        glds16(Bbase + (size_t)tt * 64 + (size_t)(h * 64) * K,
               smem + 32768 + d * 16384 + h * 4096 + tid * 8);
    };
    auto stage6 = [&](int d, int tt) {             // needed by phases q0,q1
        stA(d, tt, 0); stA(d, tt, 2);
        stB(d, tt, 0); stB(d, tt, 1); stB(d, tt, 2); stB(d, tt, 3);
    };
    auto stage2 = [&](int d, int tt) {             // needed by phases q2,q3
        stA(d, tt, 1); stA(d, tt, 3);
    };

    // read-side swizzled chunk offsets (elems); row&7 == lr&7 for all frag rows
    const int aswz0 = ((0 + lg) ^ (lr & 7)) << 3;  // k-half 0
    const int aswz1 = ((4 + lg) ^ (lr & 7)) << 3;  // k-half 1

    f32x4 acc[8][4] = {};
    const int ntile = K >> 6;

    stage6(0, 0);
    stage2(0, 0);

    s16x8 bf0[4], bf1[4];
    for (int t = 0; t < ntile; ++t) {
        const int d = t & 1, nd = d ^ 1;
        const int abase = d * 16384 + wr * 8192;
        const int bbase = 32768 + d * 16384 + (wc >> 1) * 8192 + ((wc & 1) * 64 + lr) * 64;

        // ---- boundary: certify tile t's batch6 (outstanding: t's 8 -> keep <=2) ----
        asm volatile("s_waitcnt vmcnt(2)" ::: "memory");
        __builtin_amdgcn_s_barrier();
        __builtin_amdgcn_sched_barrier(0);

#pragma unroll
        for (int q = 0; q < 4; ++q) {
            if (q == 2) {
                // ---- pre-q2: certify tile t's batch2 ----
                if (t + 1 < ntile) asm volatile("s_waitcnt vmcnt(8)" ::: "memory");
                else               asm volatile("s_waitcnt vmcnt(0)" ::: "memory");
                __builtin_amdgcn_s_barrier();
                __builtin_amdgcn_sched_barrier(0);
            }
            const int r0 = (2 * q) * 16 + lr;
            const int r1 = (2 * q + 1) * 16 + lr;
            s16x8 a00 = *(const s16x8*)(smem + abase + r0 * 64 + aswz0);
            s16x8 a01 = *(const s16x8*)(smem + abase + r0 * 64 + aswz1);
            s16x8 a10 = *(const s16x8*)(smem + abase + r1 * 64 + aswz0);
            s16x8 a11 = *(const s16x8*)(smem + abase + r1 * 64 + aswz1);
            if (q == 0) {
#pragma unroll
                for (int fc = 0; fc < 4; ++fc) {
                    bf0[fc] = *(const s16x8*)(smem + bbase + fc * 1024 + aswz0);
                    bf1[fc] = *(const s16x8*)(smem + bbase + fc * 1024 + aswz1);
                }
                if (t + 1 < ntile) stage6(nd, t + 1);
            } else if (q == 1) {
                if (t + 1 < ntile) stage2(nd, t + 1);
            }
            __builtin_amdgcn_s_setprio(1);
#pragma unroll
            for (int fc = 0; fc < 4; ++fc) {       // bf0-half first: bf1 reads overlap
                acc[2 * q][fc]     = __builtin_amdgcn_mfma_f32_16x16x32_bf16(a00, bf0[fc], acc[2 * q][fc], 0, 0, 0);
                acc[2 * q + 1][fc] = __builtin_amdgcn_mfma_f32_16x16x32_bf16(a10, bf0[fc], acc[2 * q + 1][fc], 0, 0, 0);
            }
#pragma unroll
            for (int fc = 0; fc < 4; ++fc) {
                acc[2 * q][fc]     = __builtin_amdgcn_mfma_f32_16x16x32_bf16(a01, bf1[fc], acc[2 * q][fc], 0, 0, 0);
                acc[2 * q + 1][fc] = __builtin_amdgcn_mfma_f32_16x16x32_bf16(a11, bf1[fc], acc[2 * q + 1][fc], 0, 0, 0);
            }
            __builtin_amdgcn_s_setprio(0);
        }
    }
    __syncthreads();                               // drain + converge before smem reuse

    // ---- epilogue: 2 passes of 128 rows through sC (smem reuse; [128][PADE]) ----
    const int seg = (EPI == 1) ? (n0 >> 9) : 0;     // 0=q 1=k 2=v when N=1536
    const float* bias = (EPI == 1) ? (seg == 0 ? bias0 : (seg == 1 ? bias1 : bias2)) : bias0;
    u16* dst = (EPI == 1) ? (seg == 0 ? out0 : (seg == 1 ? out1 : out2)) : out0;
    const int ldo = (EPI == 1) ? 512 : N;
    const int ncol0 = (EPI == 1) ? (n0 & 511) : n0;

#pragma unroll
    for (int pass = 0; pass < 2; ++pass) {
        if (wr == pass) {                           // 4 waves own rows pass*128..+127
#pragma unroll
            for (int fc = 0; fc < 4; ++fc) {
                const int col = wc * 64 + fc * 16 + lr;
                const float bv = bias[ncol0 + col];
#pragma unroll
                for (int fr = 0; fr < 8; ++fr)
#pragma unroll
                    for (int r = 0; r < 4; ++r) {
                        const int row = fr * 16 + (lg << 2) + r;    // local 0..127
                        smem[row * PADE + col] = f2b(acc[fr][fc][r] + bv);
                    }
            }
        }
        __syncthreads();
        const int rbase = m0 + (pass << 7);
#pragma unroll
        for (int it = 0; it < 8; ++it) {
            const int idx = it * 512 + tid;         // 0..4095
            const int row = idx >> 5;
            const int c8 = (idx & 31) << 3;
            s16x8 v8 = *(const s16x8*)(smem + row * PADE + c8);
            size_t gaddr = (size_t)(rbase + row) * ldo + ncol0 + c8;
            s16x8 o = v8;
            if constexpr (EPI == 1) {
                if (seg < 2) {
#pragma unroll
                    for (int e = 0; e < 8; ++e) {
                        float v = b2f((u16)v8[e]);
                        v = (v > 0.f) ? v + 1.f : __expf(v);   // elu+1
                        o[e] = (short)f2b(v);
                    }
                }
            } else if constexpr (EPI == 2) {
                s16x8 rv = *(const s16x8*)(resid + gaddr);
#pragma unroll
                for (int e = 0; e < 8; ++e)
                    o[e] = (short)f2b(b2f((u16)v8[e]) + b2f((u16)rv[e]));
            } else if constexpr (EPI == 3) {
#pragma unroll
                for (int e = 0; e < 8; ++e)
                    o[e] = (short)f2b(fmaxf(b2f((u16)v8[e]), 0.f));
            }
            *(s16x8*)(dst + gaddr) = o;
        }
        __syncthreads();
    }
}

// ---------------- kv einsum: kv[b,h,d,m] = sum_s k*v ; ksum[b,h,d] = sum_s k ----------
__global__ __launch_bounds__(256)
void k_kv(const u16* __restrict__ kb_, const u16* __restrict__ vb_,
          float* __restrict__ kvp, float* __restrict__ ksump) {
    __shared__ float sk[64 * 68], sv[64 * 68];
    int bh = blockIdx.x, b = bh >> 3, h = bh & 7;
    int ch = blockIdx.y;
    int tid = threadIdx.x;
    int d0 = (tid & 15) << 2, m0 = (tid >> 4) << 2;
    float acc[4][4] = {};
    float ks[4] = {0.f, 0.f, 0.f, 0.f};
    size_t gbase = ((size_t)b * SEQ_ + (size_t)ch * 1024) * DM_ + h * 64;

    for (int st = 0; st < 1024; st += 64) {
#pragma unroll
        for (int i = 0; i < 2; ++i) {
            int li = tid + (i << 8);
            int r = li >> 3, c8 = (li & 7) << 3;
            s16x8 kv_ = *(const s16x8*)(kb_ + gbase + (size_t)(st + r) * DM_ + c8);
            s16x8 vv_ = *(const s16x8*)(vb_ + gbase + (size_t)(st + r) * DM_ + c8);
#pragma unroll
            for (int e = 0; e < 8; ++e) {
                sk[r * 68 + c8 + e] = b2f((u16)kv_[e]);
                sv[r * 68 + c8 + e] = b2f((u16)vv_[e]);
            }
        }
        __syncthreads();
        for (int s = 0; s < 64; ++s) {
            f32x4 kd = *(const f32x4*)(sk + s * 68 + d0);
            f32x4 vm = *(const f32x4*)(sv + s * 68 + m0);
#pragma unroll
            for (int i = 0; i < 4; ++i)
#pragma unroll
                for (int j = 0; j < 4; ++j) acc[i][j] += kd[i] * vm[j];
            if ((tid >> 4) == 0) { ks[0] += kd[0]; ks[1] += kd[1]; ks[2] += kd[2]; ks[3] += kd[3]; }
        }
        __syncthreads();
    }
    float* kvo = kvp + ((size_t)ch * 64 + bh) * 4096;
#pragma unroll
    for (int i = 0; i < 4; ++i)
#pragma unroll
        for (int j = 0; j < 4; ++j) kvo[(d0 + i) * 64 + m0 + j] = acc[i][j];
    if ((tid >> 4) == 0) {
        float* kso = ksump + ((size_t)ch * 64 + bh) * 64;
#pragma unroll
        for (int e = 0; e < 4; ++e) kso[d0 + e] = ks[e];
    }
}

// ---------------- attention apply: a = (q . kv) / (q . ksum + eps) --------------------
__global__ __launch_bounds__(256)
void k_attn(const u16* __restrict__ qb_, const float* __restrict__ kvp,
            const float* __restrict__ ksump, u16* __restrict__ ab_) {
    __shared__ float skv[64 * 64];
    __shared__ float sq[64 * 65];
    __shared__ float sks[64];
    int tid = threadIdx.x;
    int bh = blockIdx.y, b = bh >> 3, h = bh & 7;
    int s0 = blockIdx.x << 6;

    for (int i = tid; i < 4096; i += 256) {
        float v = 0.f;
#pragma unroll
        for (int c = 0; c < 4; ++c) v += kvp[((size_t)c * 64 + bh) * 4096 + i];
        skv[i] = v;
    }
    if (tid < 64) {
        float v = 0.f;
#pragma unroll
        for (int c = 0; c < 4; ++c) v += ksump[((size_t)c * 64 + bh) * 64 + tid];
        sks[tid] = v;
    }
#pragma unroll
    for (int i = 0; i < 2; ++i) {
        int li = tid + (i << 8);
        int r = li >> 3, c8 = (li & 7) << 3;
        s16x8 v = *(const s16x8*)(qb_ + ((size_t)b * SEQ_ + s0 + r) * DM_ + h * 64 + c8);
#pragma unroll
        for (int e = 0; e < 8; ++e) sq[r * 65 + c8 + e] = b2f((u16)v[e]);
    }
    __syncthreads();

    int sl = tid >> 2, m0 = (tid & 3) << 4;
    float den = 0.f;
    for (int d = 0; d < 64; ++d) den += sq[sl * 65 + d] * sks[d];
    float z = 1.f / (den + 1e-6f);

    float acc[16] = {};
    for (int d = 0; d < 64; ++d) {
        float qv = sq[sl * 65 + d];
        const f32x4* kp = (const f32x4*)(skv + d * 64 + m0);
#pragma unroll
        for (int j4 = 0; j4 < 4; ++j4) {
            f32x4 kv4 = kp[j4];
#pragma unroll
            for (int e = 0; e < 4; ++e) acc[j4 * 4 + e] += qv * kv4[e];
        }
    }
    u16* op = ab_ + ((size_t)b * SEQ_ + s0 + sl) * DM_ + h * 64 + m0;
    s16x8 o0, o1;
#pragma unroll
    for (int e = 0; e < 8; ++e) o0[e] = (short)f2b(acc[e] * z);
#pragma unroll
    for (int e = 0; e < 8; ++e) o1[e] = (short)f2b(acc[8 + e] * z);
    *(s16x8*)op = o0;
    *(s16x8*)(op + 8) = o1;
}

// ---------------- LayerNorm over 512 (bf16 in -> bf16 out) ----------------------------
__global__ __launch_bounds__(256)
void k_ln(const u16* __restrict__ in, const float* __restrict__ g,
          const float* __restrict__ be, u16* __restrict__ xb) {
    int row = blockIdx.x * 4 + (threadIdx.x >> 6);
    int l = threadIdx.x & 63;
    s16x8 raw = *(const s16x8*)(in + (size_t)row * DM_ + l * 8);
    float x[8];
#pragma unroll
    for (int e = 0; e < 8; ++e) x[e] = b2f((u16)raw[e]);
    float sum = 0.f;
#pragma unroll
    for (int e = 0; e < 8; ++e) sum += x[e];
#pragma unroll
    for (int off = 32; off > 0; off >>= 1) sum += __shfl_xor(sum, off);
    float mu = sum * (1.f / DM_);
    float sq = 0.f;
#pragma unroll
    for (int e = 0; e < 8; ++e) { float d = x[e] - mu; sq += d * d; }
#pragma unroll
    for (int off = 32; off > 0; off >>= 1) sq += __shfl_xor(sq, off);
    float rs = rsqrtf(sq * (1.f / DM_) + 1e-5f);
    int c = l * 8;
    const f32x4* gp = (const f32x4*)(g + c);
    const f32x4* bp = (const f32x4*)(be + c);
    f32x4 g0 = gp[0], g1 = gp[1], e0 = bp[0], e1 = bp[1];
    s16x8 pk;
#pragma unroll
    for (int e = 0; e < 4; ++e) pk[e] = (short)f2b((x[e] - mu) * rs * g0[e] + e0[e]);
#pragma unroll
    for (int e = 0; e < 4; ++e) pk[4 + e] = (short)f2b((x[4 + e] - mu) * rs * g1[e] + e1[e]);
    *(s16x8*)(xb + (size_t)row * DM_ + c) = pk;
}

// ---------------- fused LN2 (layer 1) + final LN + Wout dot ---------------------------
__global__ __launch_bounds__(256)
void k_ln2f(const u16* __restrict__ in, const float* __restrict__ g2,
            const float* __restrict__ b2_, const float* __restrict__ gf,
            const float* __restrict__ bf_, const float* __restrict__ wout,
            const float* __restrict__ bout, float* __restrict__ out) {
    int row = blockIdx.x * 4 + (threadIdx.x >> 6);
    int l = threadIdx.x & 63;
    s16x8 raw = *(const s16x8*)(in + (size_t)row * DM_ + l * 8);
    float x[8];
#pragma unroll
    for (int e = 0; e < 8; ++e) x[e] = b2f((u16)raw[e]);
    float sum = 0.f;
#pragma unroll
    for (int e = 0; e < 8; ++e) sum += x[e];
#pragma unroll
    for (int off = 32; off > 0; off >>= 1) sum += __shfl_xor(sum, off);
    float mu = sum * (1.f / DM_);
    float sq = 0.f;
#pragma unroll
    for (int e = 0; e < 8; ++e) { float d = x[e] - mu; sq += d * d; }
#pragma unroll
    for (int off = 32; off > 0; off >>= 1) sq += __shfl_xor(sq, off);
    float rs = rsqrtf(sq * (1.f / DM_) + 1e-5f);
    int c = l * 8;
    float t[8];
#pragma unroll
    for (int e = 0; e < 8; ++e) t[e] = (x[e] - mu) * rs * g2[c + e] + b2_[c + e];
    float sum2 = 0.f;
#pragma unroll
    for (int e = 0; e < 8; ++e) sum2 += t[e];
#pragma unroll
    for (int off = 32; off > 0; off >>= 1) sum2 += __shfl_xor(sum2, off);
    float mu2 = sum2 * (1.f / DM_);
    float sq2 = 0.f;
#pragma unroll
    for (int e = 0; e < 8; ++e) { float d = t[e] - mu2; sq2 += d * d; }
#pragma unroll
    for (int off = 32; off > 0; off >>= 1) sq2 += __shfl_xor(sq2, off);
    float rs2 = rsqrtf(sq2 * (1.f / DM_) + 1e-5f);
    float p = 0.f;
#pragma unroll
    for (int e = 0; e < 8; ++e)
        p += ((t[e] - mu2) * rs2 * gf[c + e] + bf_[c + e]) * wout[c + e];
#pragma unroll
    for (int off = 32; off > 0; off >>= 1) p += __shfl_xor(p, off);
    if (l == 0) out[row] = p + bout[0];
}

// =======================================================================================
extern "C" void kernel_launch(void* const* d_in, const int* in_sizes, int n_in,
                              void* d_out, int out_size, void* d_ws, size_t ws_size,
                              hipStream_t stream) {
    const float* emb   = (const float*)d_in[0];
    const float* W0    = (const float*)d_in[1];
    const float* b0    = (const float*)d_in[2];
    const float* Wq    = (const float*)d_in[3];
    const float* bq    = (const float*)d_in[4];
    const float* Wk    = (const float*)d_in[5];
    const float* bk    = (const float*)d_in[6];
    const float* Wv    = (const float*)d_in[7];
    const float* bv    = (const float*)d_in[8];
    const float* Wo    = (const float*)d_in[9];
    const float* bo    = (const float*)d_in[10];
    const float* ln1s  = (const float*)d_in[11];
    const float* ln1b  = (const float*)d_in[12];
    const float* W1    = (const float*)d_in[13];
    const float* b1    = (const float*)d_in[14];
    const float* W2    = (const float*)d_in[15];
    const float* b2    = (const float*)d_in[16];
    const float* ln2s  = (const float*)d_in[17];
    const float* ln2b  = (const float*)d_in[18];
    const float* lnfs  = (const float*)d_in[19];
    const float* lnfb  = (const float*)d_in[20];
    const float* Wout  = (const float*)d_in[21];
    const float* bout  = (const float*)d_in[22];
    float* out = (float*)d_out;

    char* ws = (char*)d_ws;
    size_t off = 0;
    auto alloc = [&](size_t bytes) -> void* {
        void* p = ws + off;
        off += (bytes + 255) & ~(size_t)255;
        return p;
    };
    u16* xb   = (u16*)alloc((size_t)BS_ * DM_ * 2);    // 32MB  x (bf16 stream)
    u16* qb   = (u16*)alloc((size_t)BS_ * DM_ * 2);    // 32MB  (rb aliases qb)
    u16* kb   = (u16*)alloc((size_t)BS_ * DM_ * 2);    // 32MB
    u16* vb   = (u16*)alloc((size_t)BS_ * DM_ * 2);    // 32MB
    float* kvp   = (float*)alloc((size_t)4 * 64 * 4096 * 4);
    float* ksump = (float*)alloc((size_t)4 * 64 * 64 * 4);
    u16* wp   = (u16*)alloc((size_t)4521984 * 2);      // weight pool ~9MB

    u16* rb   = qb;    // residual r (written after qb dead)
    u16* ab   = vb;    // attn output (written after vb consumed)
    u16* h1b  = kb;    // 64MB FF hidden = kb+vb regions
    u16* embp = kb;    // 40MB emb bf16 padded = kb+vb regions (dead before QKV)

    u16* W0t  = wp;                          // [512][640]
    u16* Wqkv = wp + 327680;                 // per layer [1536][512]
    u16* Wot  = Wqkv + 2 * 786432;           // per layer [512][512]
    u16* W1t  = Wot + 2 * 262144;            // per layer [1024][512]
    u16* W2t  = W1t + 2 * 524288;            // per layer [512][1024]

    k_tr_all<<<4416, dim3(32, 8), 0, stream>>>(W0, Wq, Wk, Wv, Wo, W1, W2,
                                               W0t, Wqkv, Wot, W1t, W2t);
    k_emb<<<2560, 256, 0, stream>>>(emb, embp);

    // x = emb @ W0 + b0
    k_gemm<0><<<256, 512, 0, stream>>>(embp, W0t, b0, nullptr, nullptr,
                                       nullptr, xb, nullptr, nullptr, BS_, DM_, FINP_, 2);

    for (int l = 0; l < 2; ++l) {
        // fused QKV: N=1536, feat(elu+1) on q,k
        k_gemm<1><<<768, 512, 0, stream>>>(xb, Wqkv + (size_t)l * 786432,
                                           bq + l * 512, bk + l * 512, bv + l * 512,
                                           nullptr, qb, kb, vb, BS_, 1536, 512, 6);
        k_kv<<<dim3(64, 4), 256, 0, stream>>>(kb, vb, kvp, ksump);
        k_attn<<<dim3(64, 64), 256, 0, stream>>>(qb, kvp, ksump, ab);
        // r = x + a@Wo + bo
        k_gemm<2><<<256, 512, 0, stream>>>(ab, Wot + (size_t)l * 262144,
                                           bo + l * 512, nullptr, nullptr,
                                           xb, rb, nullptr, nullptr, BS_, 512, 512, 2);
        k_ln<<<8192, 256, 0, stream>>>(rb, ln1s + l * 512, ln1b + l * 512, xb);
        // h = relu(x@W1+b1)
        k_gemm<3><<<512, 512, 0, stream>>>(xb, W1t + (size_t)l * 524288,
                                           b1 + l * 1024, nullptr, nullptr,
                                           nullptr, h1b, nullptr, nullptr, BS_, 1024, 512, 4);
        // r = x + h@W2 + b2
        k_gemm<2><<<256, 512, 0, stream>>>(h1b, W2t + (size_t)l * 524288,
                                           b2 + l * 512, nullptr, nullptr,
                                           xb, rb, nullptr, nullptr, BS_, 512, 1024, 2);
        if (l == 0)
            k_ln<<<8192, 256, 0, stream>>>(rb, ln2s, ln2b, xb);
        else
            k_ln2f<<<8192, 256, 0, stream>>>(rb, ln2s + 512, ln2b + 512,
                                             lnfs, lnfb, Wout, bout, out);
    }
}